// Round 1
// 204.776 us; speedup vs baseline: 1.0521x; 1.0521x over previous
//
#include <hip/hip_runtime.h>

#define TOPK 13
#define NCLS 80
#define EPSF 1e-9f
#define NSEG 32           // seglen 4688: worst-case ~490 candidates < CAP3 (no overflow)
#define GPB  8            // GTs per block (one per wave at selection time)
#define CAP3 512          // per-g candidate p-indices

typedef unsigned long long u64;

// 64-bit cross-lane xor shuffle (two 32-bit shuffles)
__device__ __forceinline__ u64 shfl_xor64(u64 x, int m) {
    int lo = __shfl_xor((int)(unsigned)(x & 0xFFFFFFFFull), m, 64);
    int hi = __shfl_xor((int)(unsigned)(x >> 32), m, 64);
    return ((u64)(unsigned)hi << 32) | (unsigned)lo;
}

// ---------------------------------------------------------------------------
// setup: block 0 sorts GTs by (class,g) -> gorder; blocks 1.. init
// count[P]=0 / firstg[P]=INT_MAX with int4 stores.
// ---------------------------------------------------------------------------
__global__ __launch_bounds__(256) void setup(const int* __restrict__ lbl,
                                             int* __restrict__ count,
                                             int* __restrict__ firstg,
                                             int* __restrict__ gorder, int P, int N) {
    int t = threadIdx.x;
    if (blockIdx.x == 0) {
        __shared__ int key[256];
        key[t] = (t < N) ? ((lbl[t] << 8) | t) : 0x7FFFFFFF;
        __syncthreads();
        for (int k = 2; k <= 256; k <<= 1) {
            for (int j = k >> 1; j >= 1; j >>= 1) {
                int ixj = t ^ j;
                if (ixj > t) {
                    int a = key[t], b = key[ixj];
                    bool up = ((t & k) == 0);
                    if (up ? (a > b) : (a < b)) { key[t] = b; key[ixj] = a; }
                }
                __syncthreads();
            }
        }
        if (t < N) gorder[t] = key[t] & 0xFF;
    } else {
        int base = (blockIdx.x - 1) * 1024 + t * 4;
        if (base + 3 < P) {
            *(int4*)&count[base]  = make_int4(0, 0, 0, 0);
            *(int4*)&firstg[base] = make_int4(0x7FFFFFFF, 0x7FFFFFFF, 0x7FFFFFFF, 0x7FFFFFFF);
        } else {
            for (int i = base; i < P; i++) { count[i] = 0; firstg[i] = 0x7FFFFFFF; }
        }
    }
}

// ---------------------------------------------------------------------------
// phaseA1: filter (LDS candidate buckets via atomics) + sparse exact eval
// into per-lane top-13 held as packed u64 keys, then an in-register
// shfl_xor bitonic butterfly merge (NO LDS merge buffer -> LDS 53.8KB->16.4KB,
// 2 blocks/CU -> 4 blocks/CU; 7 tail __syncthreads removed).
// key = enc(metric)<<32 | (0x7FFFFFFF - p): u64 '>' == (metric desc, p asc).
// ---------------------------------------------------------------------------
__global__ __launch_bounds__(512, 8) void phaseA1(const float* __restrict__ cls,
                                                  const float4* __restrict__ bboxp,
                                                  const float4* __restrict__ bboxg,
                                                  const int* __restrict__ lbl,
                                                  const int* __restrict__ gorder,
                                                  u64* __restrict__ cand,
                                                  int P, int N, int seglen) {
#pragma clang fp contract(off)
    const int s = blockIdx.x, tile = blockIdx.y, t = threadIdx.x;
    const int wv = t >> 6, lane = t & 63;
    const int pstart = s * seglen;
    int pend = pstart + seglen; if (pend > P) pend = P;

    __shared__ int pbuf[GPB][CAP3];   // 16384 B
    __shared__ int ctr[GPB];

    float4 gb[GPB];
#pragma unroll
    for (int j = 0; j < GPB; j++) {
        int gi8 = tile * GPB + j;
        int gj = (gi8 < N) ? gorder[gi8] : -1;
        gb[j] = (gj >= 0) ? bboxg[gj] : make_float4(0.f, 0.f, 0.f, 0.f);
    }
    if (t < GPB) ctr[t] = 0;
    __syncthreads();

    auto testapp = [&](float4 pb, int p, bool force) {
#pragma unroll
        for (int j = 0; j < GPB; j++) {
            float dx = fminf(gb[j].z, pb.z) - fmaxf(gb[j].x, pb.x);
            float dy = fminf(gb[j].w, pb.w) - fmaxf(gb[j].y, pb.y);
            bool want = ((dx > 0.0f) && (dy > 0.0f)) || force;
            if (want) {
                int slot = atomicAdd(&ctr[j], 1);
                if (slot < CAP3) pbuf[j][slot] = p;
            }
        }
    };

    // ---- HOT filter: peeled first element (forced-16), then 4x unroll ----
    int p = pstart + t;
    if (p < pend) { testapp(bboxp[p], p, t < 16); p += 512; }
    for (; p + 1536 < pend; p += 2048) {     // 4 independent loads in flight
        float4 pb0 = bboxp[p];
        float4 pb1 = bboxp[p + 512];
        float4 pb2 = bboxp[p + 1024];
        float4 pb3 = bboxp[p + 1536];
        testapp(pb0, p, false);
        testapp(pb1, p + 512, false);
        testapp(pb2, p + 1024, false);
        testapp(pb3, p + 1536, false);
    }
    for (; p < pend; p += 512) testapp(bboxp[p], p, false);
    __syncthreads();

    // ---- SPARSE exact evaluation: wave wv owns g-slot wv ----
    const int gi8 = tile * GPB + wv;
    const bool myValid = gi8 < N;
    const int gj = myValid ? gorder[gi8] : 0;
    const float4 gbw = bboxg[gj];
    const float gaw = fmaxf(gbw.z - gbw.x, 0.0f) * fmaxf(gbw.w - gbw.y, 0.0f);
    const int cidx = lbl[gj] - 1;
    const int rawtotal = ctr[wv];

    u64 K[16];                         // 13 real + 3 sentinel (pad for bitonic-16)
#pragma unroll
    for (int k = 0; k < 16; k++) K[k] = 0ull;

    auto ins = [&](u64 key) {
        if (key > K[TOPK - 1]) {
#pragma unroll
            for (int k = TOPK - 1; k >= 1; k--) {
                bool a = key > K[k - 1];
                K[k] = a ? K[k - 1] : (key > K[k] ? key : K[k]);
            }
            if (key > K[0]) K[0] = key;
        }
    };

    auto evalk = [&](float4 pb, float sc, int pp) -> u64 {
        float pa = fmaxf(pb.z - pb.x, 0.0f) * fmaxf(pb.w - pb.y, 0.0f);
        float xx1 = fmaxf(gbw.x, pb.x), yy1 = fmaxf(gbw.y, pb.y);
        float xx2 = fminf(gbw.z, pb.z), yy2 = fminf(gbw.w, pb.w);
        float inter = fmaxf(xx2 - xx1, 0.0f) * fmaxf(yy2 - yy1, 0.0f);
        float iou = inter / (((gaw + pa) - inter) + EPSF);
        float i2 = iou * iou;
        float m = sc * ((i2 * i2) * i2);
        unsigned ub = __float_as_uint(m);
        ub ^= ((unsigned)((int)ub >> 31)) | 0x80000000u;   // monotone float->uint
        return ((u64)ub << 32) | (unsigned)(0x7FFFFFFF - pp);
    };

    if (rawtotal <= CAP3) {
        int e = lane;
        for (; e + 64 < rawtotal; e += 128) {    // 2 independent gathers in flight
            int pp0 = pbuf[wv][e];
            int pp1 = pbuf[wv][e + 64];
            float4 pb0 = bboxp[pp0];
            float4 pb1 = bboxp[pp1];
            float sc0 = cls[(size_t)pp0 * NCLS + cidx];
            float sc1 = cls[(size_t)pp1 * NCLS + cidx];
            u64 k0 = evalk(pb0, sc0, pp0);
            u64 k1 = evalk(pb1, sc1, pp1);
            ins(k0);
            ins(k1);
        }
        for (; e < rawtotal; e += 64) {
            int pp = pbuf[wv][e];
            float4 pb = bboxp[pp];
            float sc = cls[(size_t)pp * NCLS + cidx];
            ins(evalk(pb, sc, pp));
        }
    } else if (myValid) {
        for (int pp = pstart + lane; pp < pend; pp += 64) {  // exact cold fallback
            float4 pb = bboxp[pp];
            float sc = cls[(size_t)pp * NCLS + cidx];
            ins(evalk(pb, sc, pp));
        }
    }

    // ---- in-register wave butterfly merge (bitonic top-16 of union) ----
    // After 6 rounds every lane holds the wave's sorted top-16.
    for (int str = 1; str < 64; str <<= 1) {
        // half-cleaner vs partner: K[i] = max(K[i], partner[15-i]) in pairs (i,15-i)
#pragma unroll
        for (int i = 0; i < 8; i++) {
            u64 pa = shfl_xor64(K[15 - i], str);
            u64 pb = shfl_xor64(K[i], str);
            u64 a = K[i], b = K[15 - i];
            K[i]      = (a > pa) ? a : pa;
            K[15 - i] = (b > pb) ? b : pb;
        }
        // bitonic cleanup network (desc), fixed indices -> stays in registers
#pragma unroll
        for (int j = 8; j >= 1; j >>= 1) {
#pragma unroll
            for (int i = 0; i < 16; i++) {
                if ((i & j) == 0) {
                    u64 a = K[i], b = K[i | j];
                    u64 mx = (a > b) ? a : b;
                    u64 mn = (a > b) ? b : a;
                    K[i] = mx; K[i | j] = mn;
                }
            }
        }
    }

    // lane-indexed pick via select chain (no runtime register indexing)
    u64 outk = 0ull;
#pragma unroll
    for (int k = 0; k < TOPK; k++) outk = (lane == k) ? K[k] : outk;
    if (lane < TOPK && myValid)
        cand[((size_t)gj * NSEG + s) * TOPK + lane] = outk;
}

// ---------------------------------------------------------------------------
// phaseA2: per GT merge NSEG*13=416 u64 keys -> exact global top-13 via a
// 512-element bitonic sort, then scatter count/firstg atomics if max > eps.
// ---------------------------------------------------------------------------
__global__ __launch_bounds__(512) void phaseA2(const u64* __restrict__ cand,
                                               int* __restrict__ count,
                                               int* __restrict__ firstg) {
    const int g = blockIdx.x;
    const int t = threadIdx.x;
    const int M = NSEG * TOPK;  // 416
    __shared__ u64 kv[512];
    kv[t] = (t < M) ? cand[(size_t)g * M + t] : 0ull;
    __syncthreads();
    for (int k = 2; k <= 512; k <<= 1) {
        for (int j = k >> 1; j >= 1; j >>= 1) {
            int ixj = t ^ j;
            if (ixj > t) {
                u64 a = kv[t], b = kv[ixj];
                bool dirFwd = ((t & k) == 0);              // descending
                bool doswap = dirFwd ? (a < b) : (a > b);
                if (doswap) { kv[t] = b; kv[ixj] = a; }
            }
            __syncthreads();
        }
    }
    const unsigned encEpsHi = __float_as_uint(EPSF) | 0x80000000u;  // enc(1e-9f)
    if (t < TOPK && (unsigned)(kv[0] >> 32) > encEpsHi) {
        int pi = 0x7FFFFFFF - (int)(unsigned)(kv[t] & 0xFFFFFFFFull);
        atomicAdd(&count[pi], 1);
        atomicMin(&firstg[pi], g);
    }
}

// ---------------------------------------------------------------------------
// phaseCF (ws path): fused resolve + all outputs, dense coalesced writes.
// ---------------------------------------------------------------------------
__global__ __launch_bounds__(256) void phaseCF(const float4* __restrict__ bboxp,
                                               const float4* __restrict__ bboxg,
                                               const int* __restrict__ lbl,
                                               const int* __restrict__ count,
                                               const int* __restrict__ firstg,
                                               float* __restrict__ out0,
                                               float* __restrict__ out1,
                                               float4* __restrict__ outcls4,
                                               float4* __restrict__ outbox4, int P, int N) {
#pragma clang fp contract(off)
    __shared__ float4 gbS[256];
    __shared__ int glS[256];
    __shared__ int clsl[256];
    int t = threadIdx.x;
    if (t < N) { gbS[t] = bboxg[t]; glS[t] = lbl[t]; }
    __syncthreads();
    int p0 = blockIdx.x * 256;
    int nloc = P - p0; if (nloc > 256) nloc = 256;
    if (t < nloc) {
        int p = p0 + t;
        int cnt = count[p];
        int gi = 0, pos = 0;
        if (cnt == 1) { gi = firstg[p]; pos = 1; }
        else if (cnt > 1) {
            float4 pb = bboxp[p];
            float pa = fmaxf(pb.z - pb.x, 0.0f) * fmaxf(pb.w - pb.y, 0.0f);
            float best = -1.0f;
            for (int g = 0; g < N; g++) {
                float4 g4 = gbS[g];
                float gar = fmaxf(g4.z - g4.x, 0.0f) * fmaxf(g4.w - g4.y, 0.0f);
                float xx1 = fmaxf(g4.x, pb.x), yy1 = fmaxf(g4.y, pb.y);
                float xx2 = fminf(g4.z, pb.z), yy2 = fminf(g4.w, pb.w);
                float inter = fmaxf(xx2 - xx1, 0.0f) * fmaxf(yy2 - yy1, 0.0f);
                float iou = inter / (((gar + pa) - inter) + EPSF);
                if (iou > best) { best = iou; gi = g; }   // strict > == first-max
            }
            pos = 1;
        }
        out0[p] = (float)gi;
        out1[p] = pos ? (float)glS[gi] : 0.0f;
        clsl[t] = glS[gi] - 1;
        outbox4[p] = gbS[gi];
    }
    __syncthreads();
    for (int f = t; f < nloc * 20; f += 256) {
        int pl = f / 20, q = f - pl * 20;
        int cl = clsl[pl], c0 = q * 4;
        float4 vv = make_float4(c0 == cl ? 1.0f : 0.0f, c0 + 1 == cl ? 1.0f : 0.0f,
                                c0 + 2 == cl ? 1.0f : 0.0f, c0 + 3 == cl ? 1.0f : 0.0f);
        outcls4[(size_t)p0 * 20 + f] = vv;
    }
}

// ---------------------------------------------------------------------------
// Fallback path (small ws): scratch aliases the output regions; split C1/C2.
// ---------------------------------------------------------------------------
__global__ __launch_bounds__(256) void phaseC1(const float4* __restrict__ bboxp,
                                               const float4* __restrict__ bboxg,
                                               const int* __restrict__ lbl,
                                               const int* __restrict__ count,
                                               const int* __restrict__ firstg,
                                               float* __restrict__ out0,
                                               float* __restrict__ out1, int P, int N) {
#pragma clang fp contract(off)
    __shared__ float4 gbS[256];
    __shared__ int glS[256];
    if (threadIdx.x < (unsigned)N) {
        gbS[threadIdx.x] = bboxg[threadIdx.x];
        glS[threadIdx.x] = lbl[threadIdx.x];
    }
    __syncthreads();
    int p = blockIdx.x * 256 + threadIdx.x;
    if (p >= P) return;
    int cnt = count[p];
    int gi = 0, pos = 0;
    if (cnt == 1) { gi = firstg[p]; pos = 1; }
    else if (cnt > 1) {
        float4 pb = bboxp[p];
        float pa = fmaxf(pb.z - pb.x, 0.0f) * fmaxf(pb.w - pb.y, 0.0f);
        float best = -1.0f;
        for (int g = 0; g < N; g++) {
            float4 g4 = gbS[g];
            float gar = fmaxf(g4.z - g4.x, 0.0f) * fmaxf(g4.w - g4.y, 0.0f);
            float xx1 = fmaxf(g4.x, pb.x), yy1 = fmaxf(g4.y, pb.y);
            float xx2 = fminf(g4.z, pb.z), yy2 = fminf(g4.w, pb.w);
            float inter = fmaxf(xx2 - xx1, 0.0f) * fmaxf(yy2 - yy1, 0.0f);
            float iou = inter / (((gar + pa) - inter) + EPSF);
            if (iou > best) { best = iou; gi = g; }
        }
        pos = 1;
    }
    out0[p] = (float)gi;
    out1[p] = pos ? (float)glS[gi] : 0.0f;
}

__global__ __launch_bounds__(256) void phaseC2(const float4* __restrict__ bboxg,
                                               const int* __restrict__ lbl,
                                               const float* __restrict__ out0,
                                               float* __restrict__ outcls,
                                               float* __restrict__ outbox, int P, int N) {
    __shared__ float gbb[256 * 4];
    __shared__ int glS[256];
    __shared__ int clsl[256];
    __shared__ int gil[256];
    int tid = threadIdx.x;
    if (tid < N) {
        float4 b = bboxg[tid];
        gbb[tid * 4 + 0] = b.x; gbb[tid * 4 + 1] = b.y;
        gbb[tid * 4 + 2] = b.z; gbb[tid * 4 + 3] = b.w;
        glS[tid] = lbl[tid];
    }
    __syncthreads();
    int p0 = blockIdx.x * 256;
    int nloc = P - p0; if (nloc > 256) nloc = 256;
    if (tid < nloc) {
        int gi = (int)out0[p0 + tid];
        gil[tid] = gi;
        clsl[tid] = glS[gi] - 1;
    }
    __syncthreads();
    for (int f = tid; f < nloc * NCLS; f += 256) {
        int pl = f / NCLS;
        int c  = f - pl * NCLS;
        outcls[(size_t)p0 * NCLS + f] = (c == clsl[pl]) ? 1.0f : 0.0f;
    }
    for (int f = tid; f < nloc * 4; f += 256) {
        int pl = f >> 2, k = f & 3;
        outbox[(size_t)p0 * 4 + f] = gbb[gil[pl] * 4 + k];
    }
}

extern "C" void kernel_launch(void* const* d_in, const int* in_sizes, int n_in,
                              void* d_out, int out_size, void* d_ws, size_t ws_size,
                              hipStream_t stream) {
    const float* cls_pred  = (const float*)d_in[0];
    const float* bbox_pred = (const float*)d_in[1];
    const int*   label_gt  = (const int*)d_in[2];
    const float* bbox_gt   = (const float*)d_in[3];
    int P = in_sizes[1] / 4;
    int N = in_sizes[3] / 4;

    float* out    = (float*)d_out;
    float* out0   = out;
    float* out1   = out + (size_t)P;
    float* outcls = out + (size_t)2 * P;
    float* outbox = out + (size_t)82 * P;

    int pb = (P + 255) / 256;
    int seglen = (P + NSEG - 1) / NSEG;
    int gtiles = (N + GPB - 1) / GPB;
    dim3 gridA1(NSEG, gtiles);
    int setupBlocks = 1 + (P + 1023) / 1024;
    size_t candBytes = (size_t)N * NSEG * TOPK * sizeof(u64);
    size_t needWs = (size_t)P * 8 + candBytes + (size_t)N * 4 + 64;

    if (ws_size >= needWs) {
        // ws: count[P] | firstg[P] | cand | gorder[N]
        int* count  = (int*)d_ws;
        int* firstg = count + P;
        u64* cand   = (u64*)(firstg + P);
        int* gorder = (int*)((char*)cand + candBytes);

        setup<<<setupBlocks, 256, 0, stream>>>(label_gt, count, firstg, gorder, P, N);
        phaseA1<<<gridA1, 512, 0, stream>>>(cls_pred, (const float4*)bbox_pred,
                                            (const float4*)bbox_gt, label_gt, gorder,
                                            cand, P, N, seglen);
        phaseA2<<<N, 512, 0, stream>>>(cand, count, firstg);
        phaseCF<<<pb, 256, 0, stream>>>((const float4*)bbox_pred, (const float4*)bbox_gt,
                                        label_gt, count, firstg, out0, out1,
                                        (float4*)outcls, (float4*)outbox, P, N);
    } else {
        // fallback: count/firstg in outbox region; cand/gorder in the 48MB
        // outcls region (dead until phaseC2 writes it).
        int* count  = (int*)outbox;
        int* firstg = ((int*)outbox) + P;
        u64* cand   = (u64*)outcls;
        int* gorder = (int*)((char*)cand + candBytes);

        setup<<<setupBlocks, 256, 0, stream>>>(label_gt, count, firstg, gorder, P, N);
        phaseA1<<<gridA1, 512, 0, stream>>>(cls_pred, (const float4*)bbox_pred,
                                            (const float4*)bbox_gt, label_gt, gorder,
                                            cand, P, N, seglen);
        phaseC1<<<pb, 256, 0, stream>>>((const float4*)bbox_pred, (const float4*)bbox_gt,
                                        label_gt, count, firstg, out0, out1, P, N);
        phaseC2<<<pb, 256, 0, stream>>>((const float4*)bbox_gt, label_gt, out0,
                                        outcls, outbox, P, N);
    }
}